// Round 10
// baseline (281.656 us; speedup 1.0000x reference)
//
#include <hip/hip_runtime.h>
#include <hip/hip_cooperative_groups.h>
#include <math.h>

namespace cg = cooperative_groups;

// GCN, N=50000 nodes, E=800000 edges, F_IN=128, H=128, C=16. f32 in/out; edges int32.
//
// R2: CSR-by-dst pull aggregation (no float atomics), dinv pre-scaling.
// R3-R6: scan, bf16 h1 staging, counting-sort CSR, vectorized gathers.
// R7: 4 L2-resident feature-slice passes for l1. R8: MFMA gemm1 (hi/lo split-A).
// R9: W1 pre-swizzled to MFMA fragment order (coalesced B loads).
// R10: (a) CSR build merged into ONE cooperative kernel (2 grid.sync()s; edges
//      staged in LDS once; bcur doubles as count+cursor) - was 4 kernels+memset.
//      (b) agg intermediate packed bf16 (halves l1 write + gemm2 read traffic).

#define NBUCKET_SHIFT 8                   // bucket = dst >> 8 (256 nodes/bucket)
#define BIN_CHUNK 4096                    // edges per chunk/block

typedef __bf16 bf16x8 __attribute__((ext_vector_type(8)));
typedef float  f32x4  __attribute__((ext_vector_type(4)));

__device__ __forceinline__ unsigned short pack_bf16(float f) {
    unsigned u = __float_as_uint(f);
    return (unsigned short)((u + 0x7fffu + ((u >> 16) & 1u)) >> 16);   // RNE
}

__device__ __forceinline__ unsigned pack_bf16x2(float a, float b) {
    return ((unsigned)pack_bf16(b) << 16) | pack_bf16(a);
}

__device__ __forceinline__ float2 unpack_bf16x2(unsigned u) {
    return make_float2(__uint_as_float(u << 16), __uint_as_float(u & 0xffff0000u));
}

// ---------------- cooperative CSR build ----------------
// Phase A: each block stages BIN_CHUNK edges in LDS, counts buckets, reserves
//          per-bucket relative ranges via atomicAdd on bcur (so bcur ends as
//          the final bucket counts). grid.sync.
// Phase B: every block scans bcur (196 entries) in LDS -> bucket bases, then
//          scatters its staged pairs bucket-contiguously. grid.sync.
// Phase C: block b builds bucket b: LDS dst-histogram -> rowptr+dinv, then
//          LDS-cursor scatter of src into colsrc.
__global__ __launch_bounds__(256)
void csr_coop_kernel(const int* __restrict__ src, const int* __restrict__ dst,
                     int* __restrict__ bcur, uint2* __restrict__ pairs,
                     int* __restrict__ rowptr, float* __restrict__ dinv,
                     int* __restrict__ colsrc, int E, int N, int nbuckets) {
    cg::grid_group grid = cg::this_grid();
    __shared__ uint2 spair[BIN_CHUNK];   // 32 KB
    __shared__ int lcnt[256];
    __shared__ int lbase[256];
    __shared__ int sbase[256];
    const int tid = threadIdx.x;
    const int blk = blockIdx.x;

    // ---- Phase A ----
    const int e0 = blk * BIN_CHUNK;
    const int cnt = (e0 < E) ? min(BIN_CHUNK, E - e0) : 0;
    lcnt[tid] = 0;
    __syncthreads();
    for (int i = tid; i < cnt; i += 256) {
        int s = src[e0 + i], d = dst[e0 + i];
        spair[i] = make_uint2((unsigned)s, (unsigned)d);
        atomicAdd(&lcnt[d >> NBUCKET_SHIFT], 1);
    }
    __syncthreads();
    if (tid < nbuckets) {
        int c = lcnt[tid];
        lbase[tid] = (c > 0) ? atomicAdd(&bcur[tid], c) : 0;  // relative offset
        lcnt[tid] = 0;                                        // reuse as cursor
    }
    grid.sync();

    // ---- Phase B: scan final counts (bcur) -> sbase (exclusive) ----
    int v = (tid < nbuckets) ? bcur[tid] : 0;
    sbase[tid] = v;
    __syncthreads();
#pragma unroll
    for (int off = 1; off < 256; off <<= 1) {
        int u = (tid >= off) ? sbase[tid - off] : 0;
        __syncthreads();
        sbase[tid] += u;
        __syncthreads();
    }
    int excl0 = sbase[tid] - v;
    __syncthreads();
    sbase[tid] = excl0;
    __syncthreads();
    for (int i = tid; i < cnt; i += 256) {
        uint2 p = spair[i];
        int b = (int)(p.y >> NBUCKET_SHIFT);
        int off = atomicAdd(&lcnt[b], 1);
        pairs[sbase[b] + lbase[b] + off] = p;
    }
    grid.sync();

    // ---- Phase C: build bucket blk ----
    if (blk < nbuckets) {
        const int nb0 = blk << NBUCKET_SHIFT;
        const int lo = sbase[blk];
        const int hi = lo + bcur[blk];
        lcnt[tid] = 0;
        __syncthreads();
        for (int i = lo + tid; i < hi; i += 256)
            atomicAdd(&lcnt[(int)pairs[i].y - nb0], 1);
        __syncthreads();
        int vv = lcnt[tid];
        lbase[tid] = vv;
        __syncthreads();
#pragma unroll
        for (int off = 1; off < 256; off <<= 1) {
            int u = (tid >= off) ? lbase[tid - off] : 0;
            __syncthreads();
            lbase[tid] += u;
            __syncthreads();
        }
        int excl = lbase[tid] - vv;
        int node = nb0 + tid;
        if (node < N) {
            rowptr[node] = lo + excl;
            dinv[node] = rsqrtf((float)vv + 1.0f);   // +1 self-loop
        }
        __syncthreads();
        lcnt[tid] = lo + excl;   // scatter cursor
        __syncthreads();
        for (int i = lo + tid; i < hi; i += 256) {
            uint2 p = pairs[i];
            int pos = atomicAdd(&lcnt[(int)p.y - nb0], 1);
            colsrc[pos] = (int)p.x;
        }
    }
    if (blk == 0 && tid == 0) rowptr[N] = E;
}

// ---------------- W1 -> MFMA-fragment-order bf16 pack (one-shot) --------------
__global__ __launch_bounds__(256)
void wt_kernel(const float* __restrict__ W, unsigned short* __restrict__ wtp) {
    int idx = blockIdx.x * 256 + threadIdx.x;    // 0..16383
    int j    = idx & 7;
    int lane = (idx >> 3) & 63;
    int ks   = (idx >> 9) & 3;
    int t    = idx >> 11;
    int n = t * 16 + (lane & 15);
    int k = ks * 32 + ((lane >> 4) << 3) + j;
    wtp[idx] = pack_bf16(W[k * 128 + n]);
}

// ---------------- gemm1: MFMA bf16, hi/lo split-A ----------------
__global__ __launch_bounds__(256)
void gemm1_mfma_kernel(const float* __restrict__ x, const unsigned short* __restrict__ wtp,
                       const float* __restrict__ dinv, unsigned* __restrict__ h1b, int N) {
    __shared__ float lds[4][16 * 132];   // 33792 B
    const int tid = threadIdx.x, wave = tid >> 6, lane = tid & 63;
    const int q = lane >> 4, m = lane & 15;
    const int row0 = blockIdx.x * 64 + wave * 16;
    const int row = row0 + m;
    const int rowc = (row < N) ? row : (N - 1);   // clamp (OOB rows masked at store)

    f32x4 acc[8];
#pragma unroll
    for (int t = 0; t < 8; t++) acc[t] = (f32x4)0.0f;

#pragma unroll
    for (int ks = 0; ks < 4; ks++) {
        const float4* xp = (const float4*)(x + (size_t)rowc * 128 + ks * 32 + q * 8);
        float4 f0 = xp[0], f1 = xp[1];
        float fv[8] = {f0.x, f0.y, f0.z, f0.w, f1.x, f1.y, f1.z, f1.w};
        bf16x8 ah, al;
#pragma unroll
        for (int j = 0; j < 8; j++) {
            __bf16 h = (__bf16)fv[j];
            ah[j] = h;
            al[j] = (__bf16)(fv[j] - (float)h);
        }
#pragma unroll
        for (int t = 0; t < 8; t++) {
            bf16x8 b = *(const bf16x8*)(wtp + (size_t)(t * 4 + ks) * 512 + lane * 8);
            acc[t] = __builtin_amdgcn_mfma_f32_16x16x32_bf16(ah, b, acc[t], 0, 0, 0);
            acc[t] = __builtin_amdgcn_mfma_f32_16x16x32_bf16(al, b, acc[t], 0, 0, 0);
        }
    }

#pragma unroll
    for (int t = 0; t < 8; t++)
#pragma unroll
        for (int r = 0; r < 4; r++)
            lds[wave][(q * 4 + r) * 132 + t * 16 + m] = acc[t][r];
    __syncthreads();

    const int r2 = lane >> 2, j = lane & 3;
    const int orow = row0 + r2;
    if (orow < N) {
        float dv = dinv[orow];
        const float* lrow = &lds[wave][r2 * 132];
#pragma unroll
        for (int s = 0; s < 4; s++) {
            float4 a = *(const float4*)(lrow + s * 32 + j * 8);
            float4 b = *(const float4*)(lrow + s * 32 + j * 8 + 4);
            uint4 p;
            p.x = pack_bf16x2(a.x * dv, a.y * dv);
            p.y = pack_bf16x2(a.z * dv, a.w * dv);
            p.z = pack_bf16x2(b.x * dv, b.y * dv);
            p.w = pack_bf16x2(b.z * dv, b.w * dv);
            ((uint4*)(h1b + (size_t)s * N * 16))[(size_t)orow * 4 + j] = p;
        }
    }
}

// ---------------- layer-1 pull, one 32-feature slice (bf16 in, bf16 out) ------
__global__ __launch_bounds__(256)
void l1_pass_kernel(const int* __restrict__ rowptr, const int* __restrict__ colsrc,
                    const unsigned* __restrict__ h1b_s, unsigned* __restrict__ agg_s,
                    int N) {
    const int tid = threadIdx.x;
    const int wave = tid >> 6, lane = tid & 63;
    const int n = lane >> 4;          // node 0..3 within wave
    const int g = (lane >> 2) & 3;    // edge group 0..3
    const int c = lane & 3;           // uint4 chunk 0..3
    const int d = blockIdx.x * 16 + wave * 4 + n;
    if (d >= N) return;
    const uint4* hq = (const uint4*)h1b_s;   // node row = 4 uint4

    float a[8];
#pragma unroll
    for (int j = 0; j < 8; j++) a[j] = 0.0f;

    if (g == 0) {                     // self-loop term
        uint4 v = hq[(size_t)d * 4 + c];
        float2 t;
        t = unpack_bf16x2(v.x); a[0] += t.x; a[1] += t.y;
        t = unpack_bf16x2(v.y); a[2] += t.x; a[3] += t.y;
        t = unpack_bf16x2(v.z); a[4] += t.x; a[5] += t.y;
        t = unpack_bf16x2(v.w); a[6] += t.x; a[7] += t.y;
    }

    int i = rowptr[d], end = rowptr[d + 1];
    for (; i + 8 <= end; i += 8) {    // 8 edges, 2 gathers in flight
        int sA = colsrc[i + g], sB = colsrc[i + 4 + g];
        uint4 vA = hq[(size_t)sA * 4 + c];
        uint4 vB = hq[(size_t)sB * 4 + c];
        float2 t;
        t = unpack_bf16x2(vA.x); a[0] += t.x; a[1] += t.y;
        t = unpack_bf16x2(vA.y); a[2] += t.x; a[3] += t.y;
        t = unpack_bf16x2(vA.z); a[4] += t.x; a[5] += t.y;
        t = unpack_bf16x2(vA.w); a[6] += t.x; a[7] += t.y;
        t = unpack_bf16x2(vB.x); a[0] += t.x; a[1] += t.y;
        t = unpack_bf16x2(vB.y); a[2] += t.x; a[3] += t.y;
        t = unpack_bf16x2(vB.z); a[4] += t.x; a[5] += t.y;
        t = unpack_bf16x2(vB.w); a[6] += t.x; a[7] += t.y;
    }
    for (; i + 4 <= end; i += 4) {
        int sx = colsrc[i + g];
        uint4 v = hq[(size_t)sx * 4 + c];
        float2 t;
        t = unpack_bf16x2(v.x); a[0] += t.x; a[1] += t.y;
        t = unpack_bf16x2(v.y); a[2] += t.x; a[3] += t.y;
        t = unpack_bf16x2(v.z); a[4] += t.x; a[5] += t.y;
        t = unpack_bf16x2(v.w); a[6] += t.x; a[7] += t.y;
    }
    if (i < end && g < end - i) {     // tail (<4 edges)
        int sx = colsrc[i + g];
        uint4 v = hq[(size_t)sx * 4 + c];
        float2 t;
        t = unpack_bf16x2(v.x); a[0] += t.x; a[1] += t.y;
        t = unpack_bf16x2(v.y); a[2] += t.x; a[3] += t.y;
        t = unpack_bf16x2(v.z); a[4] += t.x; a[5] += t.y;
        t = unpack_bf16x2(v.w); a[6] += t.x; a[7] += t.y;
    }

#pragma unroll
    for (int j = 0; j < 8; j++) {     // combine 4 edge groups (within 16-lane node)
        a[j] += __shfl_xor(a[j], 4, 64);
        a[j] += __shfl_xor(a[j], 8, 64);
    }
    if (g == 0) {
        uint4 p;
        p.x = pack_bf16x2(a[0], a[1]);
        p.y = pack_bf16x2(a[2], a[3]);
        p.z = pack_bf16x2(a[4], a[5]);
        p.w = pack_bf16x2(a[6], a[7]);
        ((uint4*)agg_s)[(size_t)d * 4 + c] = p;
    }
}

// ---------------- gemm2: h2s[N,16] = dinv * (relu(dinv*agg + b1) @ W2) --------
// agg is slice-major packed bf16x2: slice s base = agg + s*N*16 uints.
__global__ __launch_bounds__(256)
void gemm2_kernel(const unsigned* __restrict__ agg, const float* __restrict__ dinv,
                  const float* __restrict__ b1, const float* __restrict__ W2,
                  float* __restrict__ h2s, int N) {
    __shared__ float hs[16 * 128];
    __shared__ float w2s[128 * 16];
    const int tid = threadIdx.x;
    const int row0 = blockIdx.x * 16;

    for (int i = tid; i < 512; i += 256)
        ((float4*)w2s)[i] = ((const float4*)W2)[i];

    for (int i = tid; i < 512; i += 256) {
        int r = i >> 5, q = i & 31;           // q = 4-feat group within 128-col row
        int row = row0 + r;
        float4 v = make_float4(0.f, 0.f, 0.f, 0.f);
        if (row < N) {
            int s = q >> 3, qq = q & 7;
            uint2 u = ((const uint2*)(agg + (size_t)s * N * 16))[(size_t)row * 8 + qq];
            float2 lo2 = unpack_bf16x2(u.x), hi2 = unpack_bf16x2(u.y);
            float dv = dinv[row];
            float4 b = ((const float4*)b1)[q];
            v.x = fmaxf(lo2.x * dv + b.x, 0.f);
            v.y = fmaxf(lo2.y * dv + b.y, 0.f);
            v.z = fmaxf(hi2.x * dv + b.z, 0.f);
            v.w = fmaxf(hi2.y * dv + b.w, 0.f);
        }
        ((float4*)hs)[i] = v;
    }
    __syncthreads();

    int r = tid >> 4, c = tid & 15;
    float acc = 0.0f;
#pragma unroll 16
    for (int k = 0; k < 128; k++)
        acc = fmaf(hs[r * 128 + k], w2s[k * 16 + c], acc);

    int row = row0 + r;
    if (row < N) h2s[row * 16 + c] = acc * dinv[row];   // pre-scale for layer 2
}

// ---------------- fused layer-2 pull + log_softmax ----------------
__global__ __launch_bounds__(256)
void l2_kernel(const int* __restrict__ rowptr, const int* __restrict__ colsrc,
               const float* __restrict__ dinv, const float* __restrict__ h2s,
               const float* __restrict__ b2, float* __restrict__ out, int N) {
    const int tid = threadIdx.x;
    const int wave = tid >> 6, lane = tid & 63;
    const int g = lane >> 2;          // edge group 0..15
    const int c = lane & 3;           // float4 chunk (4 feats)
    const int d = blockIdx.x * 4 + wave;
    if (d >= N) return;
    const float4* h2q = (const float4*)h2s;  // row = 4 float4

    float4 acc = make_float4(0.f, 0.f, 0.f, 0.f);
    if (g == 0) acc = h2q[d * 4 + c];        // self-loop term
    int i = rowptr[d], end = rowptr[d + 1];
    for (; i + 16 <= end; i += 16) {
        int s = colsrc[i + g];
        float4 v = h2q[s * 4 + c];
        acc.x += v.x; acc.y += v.y; acc.z += v.z; acc.w += v.w;
    }
    if (i < end && g < end - i) {            // tail (<16 edges)
        int s = colsrc[i + g];
        float4 v = h2q[s * 4 + c];
        acc.x += v.x; acc.y += v.y; acc.z += v.z; acc.w += v.w;
    }
#pragma unroll
    for (int off = 4; off <= 32; off <<= 1) {
        acc.x += __shfl_xor(acc.x, off, 64);
        acc.y += __shfl_xor(acc.y, off, 64);
        acc.z += __shfl_xor(acc.z, off, 64);
        acc.w += __shfl_xor(acc.w, off, 64);
    }
    float dv = dinv[d];
    float4 b = ((const float4*)b2)[c];
    float4 val = make_float4(acc.x * dv + b.x, acc.y * dv + b.y,
                             acc.z * dv + b.z, acc.w * dv + b.w);
    float m = fmaxf(fmaxf(val.x, val.y), fmaxf(val.z, val.w));
    m = fmaxf(m, __shfl_xor(m, 1, 64));
    m = fmaxf(m, __shfl_xor(m, 2, 64));
    float e = expf(val.x - m) + expf(val.y - m) + expf(val.z - m) + expf(val.w - m);
    e += __shfl_xor(e, 1, 64);
    e += __shfl_xor(e, 2, 64);
    float lse = m + logf(e);
    if (g == 0)
        ((float4*)out)[d * 4 + c] =
            make_float4(val.x - lse, val.y - lse, val.z - lse, val.w - lse);
}

extern "C" void kernel_launch(void* const* d_in, const int* in_sizes, int n_in,
                              void* d_out, int out_size, void* d_ws, size_t ws_size,
                              hipStream_t stream) {
    const float* x  = (const float*)d_in[0];
    const int*  ei  = (const int*)d_in[1];
    const float* W1 = (const float*)d_in[2];
    const float* b1 = (const float*)d_in[3];
    const float* W2 = (const float*)d_in[4];
    const float* b2 = (const float*)d_in[5];
    float* out = (float*)d_out;

    const int N = in_sizes[0] / 128;   // 50000
    const int E = in_sizes[1] / 2;     // 800000
    const int* src = ei;
    const int* dst = ei + E;
    const int nbuckets = (N + 255) >> NBUCKET_SHIFT;   // 196 (< 256 required)
    const int nbins = (E + BIN_CHUNK - 1) / BIN_CHUNK; // 196
    const int ngrid = (nbins > nbuckets) ? nbins : nbuckets;   // 196 coop blocks

    // Workspace layout (4B units; prefix stays 16B-aligned):
    //   dinv    : N floats
    //   rowptr  : N+4 ints
    //   bcur    : 256 ints (bucket relative cursors -> final counts)
    //   wtp     : 128*128 bf16 in MFMA fragment order (32 KB)
    //   colsrc  : E ints (3.2 MB)
    //   pairs   : E uint2 (6.4 MB) -- dead after csr_coop; agg overlays it
    //   agg     : N*64 uints (12.8 MB bf16x2, slice-major 4 x N*16) at pairs base
    //   h1b     : N*64 uints (12.8 MB, slice-major 4 x N*16)
    //   h2s     : N*16 floats (3.2 MB)        peak ~33 MB
    float*          wsf     = (float*)d_ws;
    float*          dinv    = wsf;
    int*            rowptr  = (int*)(wsf + N);
    int*            bcur    = rowptr + N + 4;
    unsigned short* wtp     = (unsigned short*)(bcur + 256);
    int*            colsrc  = bcur + 256 + 8192;
    uint2*          pairs   = (uint2*)(colsrc + E);
    unsigned*       agg     = (unsigned*)pairs;                 // overlays pairs
    unsigned*       h1b     = agg + (size_t)N * 64;
    float*          h2s     = (float*)(h1b + (size_t)N * 64);

    // ---- CSR build (one cooperative kernel) ----
    hipMemsetAsync(bcur, 0, 256 * sizeof(int), stream);
    {
        void* args[] = {(void*)&src, (void*)&dst, (void*)&bcur, (void*)&pairs,
                        (void*)&rowptr, (void*)&dinv, (void*)&colsrc,
                        (void*)&E, (void*)&N, (void*)&nbuckets};
        hipLaunchCooperativeKernel((const void*)csr_coop_kernel, dim3(ngrid),
                                   dim3(256), args, 0, stream);
    }

    // ---- layer 1 feature transform: Wt fragment-pack + MFMA gemm1 ----
    wt_kernel<<<64, 256, 0, stream>>>(W1, wtp);
    gemm1_mfma_kernel<<<(N + 63) / 64, 256, 0, stream>>>(x, wtp, dinv, h1b, N);

    // ---- layer-1 pull, 4 L2-resident slice passes (pairs now dead -> agg) ----
    {
        int blocks = (N + 15) / 16;
        for (int s = 0; s < 4; s++)
            l1_pass_kernel<<<blocks, 256, 0, stream>>>(
                rowptr, colsrc, h1b + (size_t)s * N * 16, agg + (size_t)s * N * 16, N);
    }

    // ---- gemm2 (+bias/relu, pre-scale) ----
    gemm2_kernel<<<(N + 15) / 16, 256, 0, stream>>>(agg, dinv, b1, W2, h2s, N);

    // ---- fused pull-aggregation 2 + bias + log_softmax ----
    l2_kernel<<<(N + 3) / 4, 256, 0, stream>>>(rowptr, colsrc, dinv, h2s, b2, out, N);
}

// Round 11
// 215.973 us; speedup vs baseline: 1.3041x; 1.3041x over previous
//
#include <hip/hip_runtime.h>
#include <math.h>

// GCN, N=50000 nodes, E=800000 edges, F_IN=128, H=128, C=16. f32 in/out; edges int32.
//
// R2: CSR-by-dst pull aggregation (no float atomics), dinv pre-scaling.
// R3-R6: scan, bf16 h1 staging, counting-sort CSR, vectorized gathers.
// R7: 4 L2-resident feature-slice passes for l1. R8: MFMA gemm1 (hi/lo split-A).
// R9: W1 pre-swizzled to MFMA fragment order (coalesced B loads).
// R10b (kept): agg intermediate packed bf16 (halves l1 write + gemm2 read).
// R11: REVERT R10a cooperative CSR mono-kernel (71 us @ 7.7% occupancy — grid.sync
//      pinned all phases at 196 blocks; separate kernels run each phase at full
//      occupancy). Back to 4-kernel CSR build.

#define NBUCKET_SHIFT 8                   // bucket = dst >> 8 (256 nodes/bucket)
#define BIN_CHUNK 4096                    // edges per binning block

typedef __bf16 bf16x8 __attribute__((ext_vector_type(8)));
typedef float  f32x4  __attribute__((ext_vector_type(4)));

__device__ __forceinline__ unsigned short pack_bf16(float f) {
    unsigned u = __float_as_uint(f);
    return (unsigned short)((u + 0x7fffu + ((u >> 16) & 1u)) >> 16);   // RNE
}

__device__ __forceinline__ unsigned pack_bf16x2(float a, float b) {
    return ((unsigned)pack_bf16(b) << 16) | pack_bf16(a);
}

__device__ __forceinline__ float2 unpack_bf16x2(unsigned u) {
    return make_float2(__uint_as_float(u << 16), __uint_as_float(u & 0xffff0000u));
}

// ---------------- CSR build phase 1: per-bucket edge counts (LDS-staged) ------
__global__ __launch_bounds__(256)
void bucket_count_kernel(const int* __restrict__ dst, int* __restrict__ bktcnt,
                         int E, int nbuckets) {
    __shared__ int cnt[256];
    const int tid = threadIdx.x;
    cnt[tid] = 0;
    __syncthreads();
    const int e0 = blockIdx.x * BIN_CHUNK;
    const int n = min(BIN_CHUNK, E - e0);
    for (int i = tid; i < n; i += 256)
        atomicAdd(&cnt[dst[e0 + i] >> NBUCKET_SHIFT], 1);
    __syncthreads();
    if (tid < nbuckets && cnt[tid] > 0) atomicAdd(&bktcnt[tid], cnt[tid]);
}

// ---------------- phase 2: scan bucket counts -> bktbase, seed bin cursors ----
__global__ __launch_bounds__(256)
void bucket_scan_kernel(const int* __restrict__ bktcnt, int* __restrict__ bktbase,
                        int* __restrict__ bcur, int* __restrict__ rowptrN,
                        int nbuckets, int E) {
    __shared__ int sm[256];
    const int t = threadIdx.x;
    int v = (t < nbuckets) ? bktcnt[t] : 0;
    sm[t] = v;
    __syncthreads();
#pragma unroll
    for (int off = 1; off < 256; off <<= 1) {
        int u = (t >= off) ? sm[t - off] : 0;
        __syncthreads();
        sm[t] += u;
        __syncthreads();
    }
    int excl = sm[t] - v;
    if (t < nbuckets) { bktbase[t] = excl; bcur[t] = excl; }
    if (t == nbuckets - 1) bktbase[nbuckets] = excl + v;   // == E
    if (t == 0) *rowptrN = E;
}

// ---------------- phase 3: bin edges into bucket-major pair array -------------
__global__ __launch_bounds__(256)
void bin_kernel(const int* __restrict__ src, const int* __restrict__ dst,
                int* __restrict__ bcur, uint2* __restrict__ pairs, int E, int nbuckets) {
    __shared__ uint2 spair[BIN_CHUNK];   // 32 KB
    __shared__ int bcnt[256];
    __shared__ int bbase[256];
    const int tid = threadIdx.x;
    const int e0 = blockIdx.x * BIN_CHUNK;
    const int cnt = min(BIN_CHUNK, E - e0);

    if (tid < nbuckets) bcnt[tid] = 0;
    __syncthreads();

    for (int i = tid; i < cnt; i += 256) {
        int s = src[e0 + i], d = dst[e0 + i];
        spair[i] = make_uint2((unsigned)s, (unsigned)d);
        atomicAdd(&bcnt[d >> NBUCKET_SHIFT], 1);
    }
    __syncthreads();

    if (tid < nbuckets) {
        int c = bcnt[tid];
        bbase[tid] = (c > 0) ? atomicAdd(&bcur[tid], c) : 0;
        bcnt[tid] = 0;   // reuse as local cursor
    }
    __syncthreads();

    for (int i = tid; i < cnt; i += 256) {
        uint2 p = spair[i];
        int b = (int)(p.y >> NBUCKET_SHIFT);
        int off = atomicAdd(&bcnt[b], 1);
        pairs[bbase[b] + off] = p;
    }
}

// ---------------- phase 4: per-bucket rowptr + dinv + colsrc ------------------
__global__ __launch_bounds__(256)
void bucket_build_kernel(const int* __restrict__ bktbase, const uint2* __restrict__ pairs,
                         int* __restrict__ rowptr, float* __restrict__ dinv,
                         int* __restrict__ colsrc, int N) {
    __shared__ int cnt[256];
    __shared__ int sm[256];
    const int tid = threadIdx.x;
    const int nb0 = blockIdx.x << NBUCKET_SHIFT;
    const int lo = bktbase[blockIdx.x], hi = bktbase[blockIdx.x + 1];

    cnt[tid] = 0;
    __syncthreads();
    for (int i = lo + tid; i < hi; i += 256)
        atomicAdd(&cnt[(int)pairs[i].y - nb0], 1);
    __syncthreads();

    int v = cnt[tid];
    sm[tid] = v;
    __syncthreads();
#pragma unroll
    for (int off = 1; off < 256; off <<= 1) {
        int u = (tid >= off) ? sm[tid - off] : 0;
        __syncthreads();
        sm[tid] += u;
        __syncthreads();
    }
    int excl = sm[tid] - v;
    int node = nb0 + tid;
    if (node < N) {
        rowptr[node] = lo + excl;
        dinv[node] = rsqrtf((float)v + 1.0f);   // +1 self-loop
    }
    __syncthreads();
    cnt[tid] = lo + excl;   // reuse as scatter cursor
    __syncthreads();
    for (int i = lo + tid; i < hi; i += 256) {
        uint2 p = pairs[i];
        int pos = atomicAdd(&cnt[(int)p.y - nb0], 1);
        colsrc[pos] = (int)p.x;
    }
}

// ---------------- W1 -> MFMA-fragment-order bf16 pack (one-shot) --------------
__global__ __launch_bounds__(256)
void wt_kernel(const float* __restrict__ W, unsigned short* __restrict__ wtp) {
    int idx = blockIdx.x * 256 + threadIdx.x;    // 0..16383
    int j    = idx & 7;
    int lane = (idx >> 3) & 63;
    int ks   = (idx >> 9) & 3;
    int t    = idx >> 11;
    int n = t * 16 + (lane & 15);
    int k = ks * 32 + ((lane >> 4) << 3) + j;
    wtp[idx] = pack_bf16(W[k * 128 + n]);
}

// ---------------- gemm1: MFMA bf16, hi/lo split-A ----------------
__global__ __launch_bounds__(256)
void gemm1_mfma_kernel(const float* __restrict__ x, const unsigned short* __restrict__ wtp,
                       const float* __restrict__ dinv, unsigned* __restrict__ h1b, int N) {
    __shared__ float lds[4][16 * 132];   // 33792 B
    const int tid = threadIdx.x, wave = tid >> 6, lane = tid & 63;
    const int q = lane >> 4, m = lane & 15;
    const int row0 = blockIdx.x * 64 + wave * 16;
    const int row = row0 + m;
    const int rowc = (row < N) ? row : (N - 1);   // clamp (OOB rows masked at store)

    f32x4 acc[8];
#pragma unroll
    for (int t = 0; t < 8; t++) acc[t] = (f32x4)0.0f;

#pragma unroll
    for (int ks = 0; ks < 4; ks++) {
        const float4* xp = (const float4*)(x + (size_t)rowc * 128 + ks * 32 + q * 8);
        float4 f0 = xp[0], f1 = xp[1];
        float fv[8] = {f0.x, f0.y, f0.z, f0.w, f1.x, f1.y, f1.z, f1.w};
        bf16x8 ah, al;
#pragma unroll
        for (int j = 0; j < 8; j++) {
            __bf16 h = (__bf16)fv[j];
            ah[j] = h;
            al[j] = (__bf16)(fv[j] - (float)h);
        }
#pragma unroll
        for (int t = 0; t < 8; t++) {
            bf16x8 b = *(const bf16x8*)(wtp + (size_t)(t * 4 + ks) * 512 + lane * 8);
            acc[t] = __builtin_amdgcn_mfma_f32_16x16x32_bf16(ah, b, acc[t], 0, 0, 0);
            acc[t] = __builtin_amdgcn_mfma_f32_16x16x32_bf16(al, b, acc[t], 0, 0, 0);
        }
    }

#pragma unroll
    for (int t = 0; t < 8; t++)
#pragma unroll
        for (int r = 0; r < 4; r++)
            lds[wave][(q * 4 + r) * 132 + t * 16 + m] = acc[t][r];
    __syncthreads();

    const int r2 = lane >> 2, j = lane & 3;
    const int orow = row0 + r2;
    if (orow < N) {
        float dv = dinv[orow];
        const float* lrow = &lds[wave][r2 * 132];
#pragma unroll
        for (int s = 0; s < 4; s++) {
            float4 a = *(const float4*)(lrow + s * 32 + j * 8);
            float4 b = *(const float4*)(lrow + s * 32 + j * 8 + 4);
            uint4 p;
            p.x = pack_bf16x2(a.x * dv, a.y * dv);
            p.y = pack_bf16x2(a.z * dv, a.w * dv);
            p.z = pack_bf16x2(b.x * dv, b.y * dv);
            p.w = pack_bf16x2(b.z * dv, b.w * dv);
            ((uint4*)(h1b + (size_t)s * N * 16))[(size_t)orow * 4 + j] = p;
        }
    }
}

// ---------------- layer-1 pull, one 32-feature slice (bf16 in, bf16 out) ------
__global__ __launch_bounds__(256)
void l1_pass_kernel(const int* __restrict__ rowptr, const int* __restrict__ colsrc,
                    const unsigned* __restrict__ h1b_s, unsigned* __restrict__ agg_s,
                    int N) {
    const int tid = threadIdx.x;
    const int wave = tid >> 6, lane = tid & 63;
    const int n = lane >> 4;          // node 0..3 within wave
    const int g = (lane >> 2) & 3;    // edge group 0..3
    const int c = lane & 3;           // uint4 chunk 0..3
    const int d = blockIdx.x * 16 + wave * 4 + n;
    if (d >= N) return;
    const uint4* hq = (const uint4*)h1b_s;   // node row = 4 uint4

    float a[8];
#pragma unroll
    for (int j = 0; j < 8; j++) a[j] = 0.0f;

    if (g == 0) {                     // self-loop term
        uint4 v = hq[(size_t)d * 4 + c];
        float2 t;
        t = unpack_bf16x2(v.x); a[0] += t.x; a[1] += t.y;
        t = unpack_bf16x2(v.y); a[2] += t.x; a[3] += t.y;
        t = unpack_bf16x2(v.z); a[4] += t.x; a[5] += t.y;
        t = unpack_bf16x2(v.w); a[6] += t.x; a[7] += t.y;
    }

    int i = rowptr[d], end = rowptr[d + 1];
    for (; i + 8 <= end; i += 8) {    // 8 edges, 2 gathers in flight
        int sA = colsrc[i + g], sB = colsrc[i + 4 + g];
        uint4 vA = hq[(size_t)sA * 4 + c];
        uint4 vB = hq[(size_t)sB * 4 + c];
        float2 t;
        t = unpack_bf16x2(vA.x); a[0] += t.x; a[1] += t.y;
        t = unpack_bf16x2(vA.y); a[2] += t.x; a[3] += t.y;
        t = unpack_bf16x2(vA.z); a[4] += t.x; a[5] += t.y;
        t = unpack_bf16x2(vA.w); a[6] += t.x; a[7] += t.y;
        t = unpack_bf16x2(vB.x); a[0] += t.x; a[1] += t.y;
        t = unpack_bf16x2(vB.y); a[2] += t.x; a[3] += t.y;
        t = unpack_bf16x2(vB.z); a[4] += t.x; a[5] += t.y;
        t = unpack_bf16x2(vB.w); a[6] += t.x; a[7] += t.y;
    }
    for (; i + 4 <= end; i += 4) {
        int sx = colsrc[i + g];
        uint4 v = hq[(size_t)sx * 4 + c];
        float2 t;
        t = unpack_bf16x2(v.x); a[0] += t.x; a[1] += t.y;
        t = unpack_bf16x2(v.y); a[2] += t.x; a[3] += t.y;
        t = unpack_bf16x2(v.z); a[4] += t.x; a[5] += t.y;
        t = unpack_bf16x2(v.w); a[6] += t.x; a[7] += t.y;
    }
    if (i < end && g < end - i) {     // tail (<4 edges)
        int sx = colsrc[i + g];
        uint4 v = hq[(size_t)sx * 4 + c];
        float2 t;
        t = unpack_bf16x2(v.x); a[0] += t.x; a[1] += t.y;
        t = unpack_bf16x2(v.y); a[2] += t.x; a[3] += t.y;
        t = unpack_bf16x2(v.z); a[4] += t.x; a[5] += t.y;
        t = unpack_bf16x2(v.w); a[6] += t.x; a[7] += t.y;
    }

#pragma unroll
    for (int j = 0; j < 8; j++) {     // combine 4 edge groups (within 16-lane node)
        a[j] += __shfl_xor(a[j], 4, 64);
        a[j] += __shfl_xor(a[j], 8, 64);
    }
    if (g == 0) {
        uint4 p;
        p.x = pack_bf16x2(a[0], a[1]);
        p.y = pack_bf16x2(a[2], a[3]);
        p.z = pack_bf16x2(a[4], a[5]);
        p.w = pack_bf16x2(a[6], a[7]);
        ((uint4*)agg_s)[(size_t)d * 4 + c] = p;
    }
}

// ---------------- gemm2: h2s[N,16] = dinv * (relu(dinv*agg + b1) @ W2) --------
// agg is slice-major packed bf16x2: slice s base = agg + s*N*16 uints.
__global__ __launch_bounds__(256)
void gemm2_kernel(const unsigned* __restrict__ agg, const float* __restrict__ dinv,
                  const float* __restrict__ b1, const float* __restrict__ W2,
                  float* __restrict__ h2s, int N) {
    __shared__ float hs[16 * 128];
    __shared__ float w2s[128 * 16];
    const int tid = threadIdx.x;
    const int row0 = blockIdx.x * 16;

    for (int i = tid; i < 512; i += 256)
        ((float4*)w2s)[i] = ((const float4*)W2)[i];

    for (int i = tid; i < 512; i += 256) {
        int r = i >> 5, q = i & 31;           // q = 4-feat group within 128-col row
        int row = row0 + r;
        float4 v = make_float4(0.f, 0.f, 0.f, 0.f);
        if (row < N) {
            int s = q >> 3, qq = q & 7;
            uint2 u = ((const uint2*)(agg + (size_t)s * N * 16))[(size_t)row * 8 + qq];
            float2 lo2 = unpack_bf16x2(u.x), hi2 = unpack_bf16x2(u.y);
            float dv = dinv[row];
            float4 b = ((const float4*)b1)[q];
            v.x = fmaxf(lo2.x * dv + b.x, 0.f);
            v.y = fmaxf(lo2.y * dv + b.y, 0.f);
            v.z = fmaxf(hi2.x * dv + b.z, 0.f);
            v.w = fmaxf(hi2.y * dv + b.w, 0.f);
        }
        ((float4*)hs)[i] = v;
    }
    __syncthreads();

    int r = tid >> 4, c = tid & 15;
    float acc = 0.0f;
#pragma unroll 16
    for (int k = 0; k < 128; k++)
        acc = fmaf(hs[r * 128 + k], w2s[k * 16 + c], acc);

    int row = row0 + r;
    if (row < N) h2s[row * 16 + c] = acc * dinv[row];   // pre-scale for layer 2
}

// ---------------- fused layer-2 pull + log_softmax ----------------
__global__ __launch_bounds__(256)
void l2_kernel(const int* __restrict__ rowptr, const int* __restrict__ colsrc,
               const float* __restrict__ dinv, const float* __restrict__ h2s,
               const float* __restrict__ b2, float* __restrict__ out, int N) {
    const int tid = threadIdx.x;
    const int wave = tid >> 6, lane = tid & 63;
    const int g = lane >> 2;          // edge group 0..15
    const int c = lane & 3;           // float4 chunk (4 feats)
    const int d = blockIdx.x * 4 + wave;
    if (d >= N) return;
    const float4* h2q = (const float4*)h2s;  // row = 4 float4

    float4 acc = make_float4(0.f, 0.f, 0.f, 0.f);
    if (g == 0) acc = h2q[d * 4 + c];        // self-loop term
    int i = rowptr[d], end = rowptr[d + 1];
    for (; i + 16 <= end; i += 16) {
        int s = colsrc[i + g];
        float4 v = h2q[s * 4 + c];
        acc.x += v.x; acc.y += v.y; acc.z += v.z; acc.w += v.w;
    }
    if (i < end && g < end - i) {            // tail (<16 edges)
        int s = colsrc[i + g];
        float4 v = h2q[s * 4 + c];
        acc.x += v.x; acc.y += v.y; acc.z += v.z; acc.w += v.w;
    }
#pragma unroll
    for (int off = 4; off <= 32; off <<= 1) {
        acc.x += __shfl_xor(acc.x, off, 64);
        acc.y += __shfl_xor(acc.y, off, 64);
        acc.z += __shfl_xor(acc.z, off, 64);
        acc.w += __shfl_xor(acc.w, off, 64);
    }
    float dv = dinv[d];
    float4 b = ((const float4*)b2)[c];
    float4 val = make_float4(acc.x * dv + b.x, acc.y * dv + b.y,
                             acc.z * dv + b.z, acc.w * dv + b.w);
    float m = fmaxf(fmaxf(val.x, val.y), fmaxf(val.z, val.w));
    m = fmaxf(m, __shfl_xor(m, 1, 64));
    m = fmaxf(m, __shfl_xor(m, 2, 64));
    float e = expf(val.x - m) + expf(val.y - m) + expf(val.z - m) + expf(val.w - m);
    e += __shfl_xor(e, 1, 64);
    e += __shfl_xor(e, 2, 64);
    float lse = m + logf(e);
    if (g == 0)
        ((float4*)out)[d * 4 + c] =
            make_float4(val.x - lse, val.y - lse, val.z - lse, val.w - lse);
}

extern "C" void kernel_launch(void* const* d_in, const int* in_sizes, int n_in,
                              void* d_out, int out_size, void* d_ws, size_t ws_size,
                              hipStream_t stream) {
    const float* x  = (const float*)d_in[0];
    const int*  ei  = (const int*)d_in[1];
    const float* W1 = (const float*)d_in[2];
    const float* b1 = (const float*)d_in[3];
    const float* W2 = (const float*)d_in[4];
    const float* b2 = (const float*)d_in[5];
    float* out = (float*)d_out;

    const int N = in_sizes[0] / 128;   // 50000
    const int E = in_sizes[1] / 2;     // 800000
    const int* src = ei;
    const int* dst = ei + E;
    const int nbuckets = (N + 255) >> NBUCKET_SHIFT;   // 196 (< 256 required)
    const int nbins = (E + BIN_CHUNK - 1) / BIN_CHUNK; // 196

    // Workspace layout (4B units; prefix stays 16B-aligned):
    //   dinv    : N floats
    //   rowptr  : N+4 ints
    //   bktcnt  : 256 ints
    //   bktbase : 260 ints
    //   bcur    : 256 ints
    //   wtp     : 128*128 bf16 in MFMA fragment order (32 KB = 8192 int slots)
    //   colsrc  : E ints (3.2 MB)
    //   pairs   : E uint2 (6.4 MB) -- dead after bucket_build; agg overlays it
    //   agg     : N*64 uints (12.8 MB bf16x2, slice-major 4 x N*16) at pairs base
    //   h1b     : N*64 uints (12.8 MB, slice-major 4 x N*16)
    //   h2s     : N*16 floats (3.2 MB)        peak ~33 MB
    float*          wsf     = (float*)d_ws;
    float*          dinv    = wsf;
    int*            rowptr  = (int*)(wsf + N);
    int*            bktcnt  = rowptr + N + 4;
    int*            bktbase = bktcnt + 256;
    int*            bcur    = bktbase + 260;
    unsigned short* wtp     = (unsigned short*)(bcur + 256);
    int*            colsrc  = bcur + 256 + 8192;
    uint2*          pairs   = (uint2*)(colsrc + E);
    unsigned*       agg     = (unsigned*)pairs;                 // overlays pairs
    unsigned*       h1b     = agg + (size_t)N * 64;
    float*          h2s     = (float*)(h1b + (size_t)N * 64);

    // ---- CSR build (4 kernels, full occupancy per phase) ----
    hipMemsetAsync(bktcnt, 0, 256 * sizeof(int), stream);
    bucket_count_kernel<<<nbins, 256, 0, stream>>>(dst, bktcnt, E, nbuckets);
    bucket_scan_kernel<<<1, 256, 0, stream>>>(bktcnt, bktbase, bcur, rowptr + N,
                                              nbuckets, E);
    bin_kernel<<<nbins, 256, 0, stream>>>(src, dst, bcur, pairs, E, nbuckets);
    bucket_build_kernel<<<nbuckets, 256, 0, stream>>>(bktbase, pairs, rowptr,
                                                      dinv, colsrc, N);

    // ---- layer 1 feature transform: Wt fragment-pack + MFMA gemm1 ----
    wt_kernel<<<64, 256, 0, stream>>>(W1, wtp);
    gemm1_mfma_kernel<<<(N + 63) / 64, 256, 0, stream>>>(x, wtp, dinv, h1b, N);

    // ---- layer-1 pull, 4 L2-resident slice passes (pairs now dead -> agg) ----
    {
        int blocks = (N + 15) / 16;
        for (int s = 0; s < 4; s++)
            l1_pass_kernel<<<blocks, 256, 0, stream>>>(
                rowptr, colsrc, h1b + (size_t)s * N * 16, agg + (size_t)s * N * 16, N);
    }

    // ---- gemm2 (+bias/relu, pre-scale) ----
    gemm2_kernel<<<(N + 15) / 16, 256, 0, stream>>>(agg, dinv, b1, W2, h2s, N);

    // ---- fused pull-aggregation 2 + bias + log_softmax ----
    l2_kernel<<<(N + 3) / 4, 256, 0, stream>>>(rowptr, colsrc, dinv, h2s, b2, out, N);
}

// Round 12
// 215.682 us; speedup vs baseline: 1.3059x; 1.0013x over previous
//
#include <hip/hip_runtime.h>
#include <math.h>

// GCN, N=50000 nodes, E=800000 edges, F_IN=128, H=128, C=16. f32 in/out; edges int32.
//
// R2: CSR-by-dst pull aggregation (no float atomics), dinv pre-scaling.
// R3-R6: scan, bf16 h1 staging, counting-sort CSR, vectorized gathers.
// R7: L2-resident feature-slice passes for l1. R8: MFMA gemm1 (hi/lo split-A).
// R9: W1 pre-swizzled to MFMA fragment order. R10b: bf16 packed agg.
// R11: reverted R10a coop CSR (grid.sync pinned occupancy at 7.7% -> 71 us).
// R12: l1 pull = 2 passes x 2 slices: one colsrc index feeds two independent
//      gathers (2x MLP per lane, half the index re-reads / loop overhead).
//      L2-hit-latency was the l1 bottleneck, not BW.

#define NBUCKET_SHIFT 8                   // bucket = dst >> 8 (256 nodes/bucket)
#define BIN_CHUNK 4096                    // edges per binning block

typedef __bf16 bf16x8 __attribute__((ext_vector_type(8)));
typedef float  f32x4  __attribute__((ext_vector_type(4)));

__device__ __forceinline__ unsigned short pack_bf16(float f) {
    unsigned u = __float_as_uint(f);
    return (unsigned short)((u + 0x7fffu + ((u >> 16) & 1u)) >> 16);   // RNE
}

__device__ __forceinline__ unsigned pack_bf16x2(float a, float b) {
    return ((unsigned)pack_bf16(b) << 16) | pack_bf16(a);
}

__device__ __forceinline__ float2 unpack_bf16x2(unsigned u) {
    return make_float2(__uint_as_float(u << 16), __uint_as_float(u & 0xffff0000u));
}

__device__ __forceinline__ void acc_u4(float* a, uint4 v) {
    float2 t;
    t = unpack_bf16x2(v.x); a[0] += t.x; a[1] += t.y;
    t = unpack_bf16x2(v.y); a[2] += t.x; a[3] += t.y;
    t = unpack_bf16x2(v.z); a[4] += t.x; a[5] += t.y;
    t = unpack_bf16x2(v.w); a[6] += t.x; a[7] += t.y;
}

// ---------------- CSR build phase 1: per-bucket edge counts (LDS-staged) ------
__global__ __launch_bounds__(256)
void bucket_count_kernel(const int* __restrict__ dst, int* __restrict__ bktcnt,
                         int E, int nbuckets) {
    __shared__ int cnt[256];
    const int tid = threadIdx.x;
    cnt[tid] = 0;
    __syncthreads();
    const int e0 = blockIdx.x * BIN_CHUNK;
    const int n = min(BIN_CHUNK, E - e0);
    for (int i = tid; i < n; i += 256)
        atomicAdd(&cnt[dst[e0 + i] >> NBUCKET_SHIFT], 1);
    __syncthreads();
    if (tid < nbuckets && cnt[tid] > 0) atomicAdd(&bktcnt[tid], cnt[tid]);
}

// ---------------- phase 2: scan bucket counts -> bktbase, seed bin cursors ----
__global__ __launch_bounds__(256)
void bucket_scan_kernel(const int* __restrict__ bktcnt, int* __restrict__ bktbase,
                        int* __restrict__ bcur, int* __restrict__ rowptrN,
                        int nbuckets, int E) {
    __shared__ int sm[256];
    const int t = threadIdx.x;
    int v = (t < nbuckets) ? bktcnt[t] : 0;
    sm[t] = v;
    __syncthreads();
#pragma unroll
    for (int off = 1; off < 256; off <<= 1) {
        int u = (t >= off) ? sm[t - off] : 0;
        __syncthreads();
        sm[t] += u;
        __syncthreads();
    }
    int excl = sm[t] - v;
    if (t < nbuckets) { bktbase[t] = excl; bcur[t] = excl; }
    if (t == nbuckets - 1) bktbase[nbuckets] = excl + v;   // == E
    if (t == 0) *rowptrN = E;
}

// ---------------- phase 3: bin edges into bucket-major pair array -------------
__global__ __launch_bounds__(256)
void bin_kernel(const int* __restrict__ src, const int* __restrict__ dst,
                int* __restrict__ bcur, uint2* __restrict__ pairs, int E, int nbuckets) {
    __shared__ uint2 spair[BIN_CHUNK];   // 32 KB
    __shared__ int bcnt[256];
    __shared__ int bbase[256];
    const int tid = threadIdx.x;
    const int e0 = blockIdx.x * BIN_CHUNK;
    const int cnt = min(BIN_CHUNK, E - e0);

    if (tid < nbuckets) bcnt[tid] = 0;
    __syncthreads();

    for (int i = tid; i < cnt; i += 256) {
        int s = src[e0 + i], d = dst[e0 + i];
        spair[i] = make_uint2((unsigned)s, (unsigned)d);
        atomicAdd(&bcnt[d >> NBUCKET_SHIFT], 1);
    }
    __syncthreads();

    if (tid < nbuckets) {
        int c = bcnt[tid];
        bbase[tid] = (c > 0) ? atomicAdd(&bcur[tid], c) : 0;
        bcnt[tid] = 0;   // reuse as local cursor
    }
    __syncthreads();

    for (int i = tid; i < cnt; i += 256) {
        uint2 p = spair[i];
        int b = (int)(p.y >> NBUCKET_SHIFT);
        int off = atomicAdd(&bcnt[b], 1);
        pairs[bbase[b] + off] = p;
    }
}

// ---------------- phase 4: per-bucket rowptr + dinv + colsrc ------------------
__global__ __launch_bounds__(256)
void bucket_build_kernel(const int* __restrict__ bktbase, const uint2* __restrict__ pairs,
                         int* __restrict__ rowptr, float* __restrict__ dinv,
                         int* __restrict__ colsrc, int N) {
    __shared__ int cnt[256];
    __shared__ int sm[256];
    const int tid = threadIdx.x;
    const int nb0 = blockIdx.x << NBUCKET_SHIFT;
    const int lo = bktbase[blockIdx.x], hi = bktbase[blockIdx.x + 1];

    cnt[tid] = 0;
    __syncthreads();
    for (int i = lo + tid; i < hi; i += 256)
        atomicAdd(&cnt[(int)pairs[i].y - nb0], 1);
    __syncthreads();

    int v = cnt[tid];
    sm[tid] = v;
    __syncthreads();
#pragma unroll
    for (int off = 1; off < 256; off <<= 1) {
        int u = (tid >= off) ? sm[tid - off] : 0;
        __syncthreads();
        sm[tid] += u;
        __syncthreads();
    }
    int excl = sm[tid] - v;
    int node = nb0 + tid;
    if (node < N) {
        rowptr[node] = lo + excl;
        dinv[node] = rsqrtf((float)v + 1.0f);   // +1 self-loop
    }
    __syncthreads();
    cnt[tid] = lo + excl;   // reuse as scatter cursor
    __syncthreads();
    for (int i = lo + tid; i < hi; i += 256) {
        uint2 p = pairs[i];
        int pos = atomicAdd(&cnt[(int)p.y - nb0], 1);
        colsrc[pos] = (int)p.x;
    }
}

// ---------------- W1 -> MFMA-fragment-order bf16 pack (one-shot) --------------
__global__ __launch_bounds__(256)
void wt_kernel(const float* __restrict__ W, unsigned short* __restrict__ wtp) {
    int idx = blockIdx.x * 256 + threadIdx.x;    // 0..16383
    int j    = idx & 7;
    int lane = (idx >> 3) & 63;
    int ks   = (idx >> 9) & 3;
    int t    = idx >> 11;
    int n = t * 16 + (lane & 15);
    int k = ks * 32 + ((lane >> 4) << 3) + j;
    wtp[idx] = pack_bf16(W[k * 128 + n]);
}

// ---------------- gemm1: MFMA bf16, hi/lo split-A ----------------
__global__ __launch_bounds__(256)
void gemm1_mfma_kernel(const float* __restrict__ x, const unsigned short* __restrict__ wtp,
                       const float* __restrict__ dinv, unsigned* __restrict__ h1b, int N) {
    __shared__ float lds[4][16 * 132];   // 33792 B
    const int tid = threadIdx.x, wave = tid >> 6, lane = tid & 63;
    const int q = lane >> 4, m = lane & 15;
    const int row0 = blockIdx.x * 64 + wave * 16;
    const int row = row0 + m;
    const int rowc = (row < N) ? row : (N - 1);   // clamp (OOB rows masked at store)

    f32x4 acc[8];
#pragma unroll
    for (int t = 0; t < 8; t++) acc[t] = (f32x4)0.0f;

#pragma unroll
    for (int ks = 0; ks < 4; ks++) {
        const float4* xp = (const float4*)(x + (size_t)rowc * 128 + ks * 32 + q * 8);
        float4 f0 = xp[0], f1 = xp[1];
        float fv[8] = {f0.x, f0.y, f0.z, f0.w, f1.x, f1.y, f1.z, f1.w};
        bf16x8 ah, al;
#pragma unroll
        for (int j = 0; j < 8; j++) {
            __bf16 h = (__bf16)fv[j];
            ah[j] = h;
            al[j] = (__bf16)(fv[j] - (float)h);
        }
#pragma unroll
        for (int t = 0; t < 8; t++) {
            bf16x8 b = *(const bf16x8*)(wtp + (size_t)(t * 4 + ks) * 512 + lane * 8);
            acc[t] = __builtin_amdgcn_mfma_f32_16x16x32_bf16(ah, b, acc[t], 0, 0, 0);
            acc[t] = __builtin_amdgcn_mfma_f32_16x16x32_bf16(al, b, acc[t], 0, 0, 0);
        }
    }

#pragma unroll
    for (int t = 0; t < 8; t++)
#pragma unroll
        for (int r = 0; r < 4; r++)
            lds[wave][(q * 4 + r) * 132 + t * 16 + m] = acc[t][r];
    __syncthreads();

    const int r2 = lane >> 2, j = lane & 3;
    const int orow = row0 + r2;
    if (orow < N) {
        float dv = dinv[orow];
        const float* lrow = &lds[wave][r2 * 132];
#pragma unroll
        for (int s = 0; s < 4; s++) {
            float4 a = *(const float4*)(lrow + s * 32 + j * 8);
            float4 b = *(const float4*)(lrow + s * 32 + j * 8 + 4);
            uint4 p;
            p.x = pack_bf16x2(a.x * dv, a.y * dv);
            p.y = pack_bf16x2(a.z * dv, a.w * dv);
            p.z = pack_bf16x2(b.x * dv, b.y * dv);
            p.w = pack_bf16x2(b.z * dv, b.w * dv);
            ((uint4*)(h1b + (size_t)s * N * 16))[(size_t)orow * 4 + j] = p;
        }
    }
}

// ---------------- layer-1 pull: 2 slices per pass (bf16 in, bf16 out) ---------
// Wave = 4 nodes x 4 edge-groups x 4 uint4-chunks. Each colsrc index feeds TWO
// independent gathers (slice A and slice B) -> 2x MLP per index load.
__global__ __launch_bounds__(256)
void l1_pass2_kernel(const int* __restrict__ rowptr, const int* __restrict__ colsrc,
                     const unsigned* __restrict__ h1b_sa, const unsigned* __restrict__ h1b_sb,
                     unsigned* __restrict__ agg_sa, unsigned* __restrict__ agg_sb, int N) {
    const int tid = threadIdx.x;
    const int wave = tid >> 6, lane = tid & 63;
    const int n = lane >> 4;          // node 0..3 within wave
    const int g = (lane >> 2) & 3;    // edge group 0..3
    const int c = lane & 3;           // uint4 chunk 0..3
    const int d = blockIdx.x * 16 + wave * 4 + n;
    if (d >= N) return;
    const uint4* hqa = (const uint4*)h1b_sa;   // node row = 4 uint4 per slice
    const uint4* hqb = (const uint4*)h1b_sb;

    float a0[8], a1[8];
#pragma unroll
    for (int j = 0; j < 8; j++) { a0[j] = 0.0f; a1[j] = 0.0f; }

    if (g == 0) {                     // self-loop term, both slices
        acc_u4(a0, hqa[(size_t)d * 4 + c]);
        acc_u4(a1, hqb[(size_t)d * 4 + c]);
    }

    int i = rowptr[d], end = rowptr[d + 1];
    for (; i + 8 <= end; i += 8) {    // 8 edges, 4 gathers in flight per lane
        int sA = colsrc[i + g], sB = colsrc[i + 4 + g];
        uint4 vA0 = hqa[(size_t)sA * 4 + c];
        uint4 vA1 = hqb[(size_t)sA * 4 + c];
        uint4 vB0 = hqa[(size_t)sB * 4 + c];
        uint4 vB1 = hqb[(size_t)sB * 4 + c];
        acc_u4(a0, vA0); acc_u4(a1, vA1);
        acc_u4(a0, vB0); acc_u4(a1, vB1);
    }
    for (; i + 4 <= end; i += 4) {
        int sx = colsrc[i + g];
        uint4 v0 = hqa[(size_t)sx * 4 + c];
        uint4 v1 = hqb[(size_t)sx * 4 + c];
        acc_u4(a0, v0); acc_u4(a1, v1);
    }
    if (i < end && g < end - i) {     // tail (<4 edges)
        int sx = colsrc[i + g];
        uint4 v0 = hqa[(size_t)sx * 4 + c];
        uint4 v1 = hqb[(size_t)sx * 4 + c];
        acc_u4(a0, v0); acc_u4(a1, v1);
    }

#pragma unroll
    for (int j = 0; j < 8; j++) {     // combine 4 edge groups (within 16-lane node)
        a0[j] += __shfl_xor(a0[j], 4, 64);
        a0[j] += __shfl_xor(a0[j], 8, 64);
        a1[j] += __shfl_xor(a1[j], 4, 64);
        a1[j] += __shfl_xor(a1[j], 8, 64);
    }
    if (g == 0) {
        uint4 p;
        p.x = pack_bf16x2(a0[0], a0[1]);
        p.y = pack_bf16x2(a0[2], a0[3]);
        p.z = pack_bf16x2(a0[4], a0[5]);
        p.w = pack_bf16x2(a0[6], a0[7]);
        ((uint4*)agg_sa)[(size_t)d * 4 + c] = p;
        p.x = pack_bf16x2(a1[0], a1[1]);
        p.y = pack_bf16x2(a1[2], a1[3]);
        p.z = pack_bf16x2(a1[4], a1[5]);
        p.w = pack_bf16x2(a1[6], a1[7]);
        ((uint4*)agg_sb)[(size_t)d * 4 + c] = p;
    }
}

// ---------------- gemm2: h2s[N,16] = dinv * (relu(dinv*agg + b1) @ W2) --------
// agg is slice-major packed bf16x2: slice s base = agg + s*N*16 uints.
__global__ __launch_bounds__(256)
void gemm2_kernel(const unsigned* __restrict__ agg, const float* __restrict__ dinv,
                  const float* __restrict__ b1, const float* __restrict__ W2,
                  float* __restrict__ h2s, int N) {
    __shared__ float hs[16 * 128];
    __shared__ float w2s[128 * 16];
    const int tid = threadIdx.x;
    const int row0 = blockIdx.x * 16;

    for (int i = tid; i < 512; i += 256)
        ((float4*)w2s)[i] = ((const float4*)W2)[i];

    for (int i = tid; i < 512; i += 256) {
        int r = i >> 5, q = i & 31;           // q = 4-feat group within 128-col row
        int row = row0 + r;
        float4 v = make_float4(0.f, 0.f, 0.f, 0.f);
        if (row < N) {
            int s = q >> 3, qq = q & 7;
            uint2 u = ((const uint2*)(agg + (size_t)s * N * 16))[(size_t)row * 8 + qq];
            float2 lo2 = unpack_bf16x2(u.x), hi2 = unpack_bf16x2(u.y);
            float dv = dinv[row];
            float4 b = ((const float4*)b1)[q];
            v.x = fmaxf(lo2.x * dv + b.x, 0.f);
            v.y = fmaxf(lo2.y * dv + b.y, 0.f);
            v.z = fmaxf(hi2.x * dv + b.z, 0.f);
            v.w = fmaxf(hi2.y * dv + b.w, 0.f);
        }
        ((float4*)hs)[i] = v;
    }
    __syncthreads();

    int r = tid >> 4, c = tid & 15;
    float acc = 0.0f;
#pragma unroll 16
    for (int k = 0; k < 128; k++)
        acc = fmaf(hs[r * 128 + k], w2s[k * 16 + c], acc);

    int row = row0 + r;
    if (row < N) h2s[row * 16 + c] = acc * dinv[row];   // pre-scale for layer 2
}

// ---------------- fused layer-2 pull + log_softmax ----------------
__global__ __launch_bounds__(256)
void l2_kernel(const int* __restrict__ rowptr, const int* __restrict__ colsrc,
               const float* __restrict__ dinv, const float* __restrict__ h2s,
               const float* __restrict__ b2, float* __restrict__ out, int N) {
    const int tid = threadIdx.x;
    const int wave = tid >> 6, lane = tid & 63;
    const int g = lane >> 2;          // edge group 0..15
    const int c = lane & 3;           // float4 chunk (4 feats)
    const int d = blockIdx.x * 4 + wave;
    if (d >= N) return;
    const float4* h2q = (const float4*)h2s;  // row = 4 float4

    float4 acc = make_float4(0.f, 0.f, 0.f, 0.f);
    if (g == 0) acc = h2q[d * 4 + c];        // self-loop term
    int i = rowptr[d], end = rowptr[d + 1];
    for (; i + 16 <= end; i += 16) {
        int s = colsrc[i + g];
        float4 v = h2q[s * 4 + c];
        acc.x += v.x; acc.y += v.y; acc.z += v.z; acc.w += v.w;
    }
    if (i < end && g < end - i) {            // tail (<16 edges)
        int s = colsrc[i + g];
        float4 v = h2q[s * 4 + c];
        acc.x += v.x; acc.y += v.y; acc.z += v.z; acc.w += v.w;
    }
#pragma unroll
    for (int off = 4; off <= 32; off <<= 1) {
        acc.x += __shfl_xor(acc.x, off, 64);
        acc.y += __shfl_xor(acc.y, off, 64);
        acc.z += __shfl_xor(acc.z, off, 64);
        acc.w += __shfl_xor(acc.w, off, 64);
    }
    float dv = dinv[d];
    float4 b = ((const float4*)b2)[c];
    float4 val = make_float4(acc.x * dv + b.x, acc.y * dv + b.y,
                             acc.z * dv + b.z, acc.w * dv + b.w);
    float m = fmaxf(fmaxf(val.x, val.y), fmaxf(val.z, val.w));
    m = fmaxf(m, __shfl_xor(m, 1, 64));
    m = fmaxf(m, __shfl_xor(m, 2, 64));
    float e = expf(val.x - m) + expf(val.y - m) + expf(val.z - m) + expf(val.w - m);
    e += __shfl_xor(e, 1, 64);
    e += __shfl_xor(e, 2, 64);
    float lse = m + logf(e);
    if (g == 0)
        ((float4*)out)[d * 4 + c] =
            make_float4(val.x - lse, val.y - lse, val.z - lse, val.w - lse);
}

extern "C" void kernel_launch(void* const* d_in, const int* in_sizes, int n_in,
                              void* d_out, int out_size, void* d_ws, size_t ws_size,
                              hipStream_t stream) {
    const float* x  = (const float*)d_in[0];
    const int*  ei  = (const int*)d_in[1];
    const float* W1 = (const float*)d_in[2];
    const float* b1 = (const float*)d_in[3];
    const float* W2 = (const float*)d_in[4];
    const float* b2 = (const float*)d_in[5];
    float* out = (float*)d_out;

    const int N = in_sizes[0] / 128;   // 50000
    const int E = in_sizes[1] / 2;     // 800000
    const int* src = ei;
    const int* dst = ei + E;
    const int nbuckets = (N + 255) >> NBUCKET_SHIFT;   // 196 (< 256 required)
    const int nbins = (E + BIN_CHUNK - 1) / BIN_CHUNK; // 196

    // Workspace layout (4B units; prefix stays 16B-aligned):
    //   dinv    : N floats
    //   rowptr  : N+4 ints
    //   bktcnt  : 256 ints
    //   bktbase : 260 ints
    //   bcur    : 256 ints
    //   wtp     : 128*128 bf16 in MFMA fragment order (32 KB = 8192 int slots)
    //   colsrc  : E ints (3.2 MB)
    //   pairs   : E uint2 (6.4 MB) -- dead after bucket_build; agg overlays it
    //   agg     : N*64 uints (12.8 MB bf16x2, slice-major 4 x N*16) at pairs base
    //   h1b     : N*64 uints (12.8 MB, slice-major 4 x N*16)
    //   h2s     : N*16 floats (3.2 MB)        peak ~33 MB
    float*          wsf     = (float*)d_ws;
    float*          dinv    = wsf;
    int*            rowptr  = (int*)(wsf + N);
    int*            bktcnt  = rowptr + N + 4;
    int*            bktbase = bktcnt + 256;
    int*            bcur    = bktbase + 260;
    unsigned short* wtp     = (unsigned short*)(bcur + 256);
    int*            colsrc  = bcur + 256 + 8192;
    uint2*          pairs   = (uint2*)(colsrc + E);
    unsigned*       agg     = (unsigned*)pairs;                 // overlays pairs
    unsigned*       h1b     = agg + (size_t)N * 64;
    float*          h2s     = (float*)(h1b + (size_t)N * 64);

    // ---- CSR build (4 kernels, full occupancy per phase) ----
    hipMemsetAsync(bktcnt, 0, 256 * sizeof(int), stream);
    bucket_count_kernel<<<nbins, 256, 0, stream>>>(dst, bktcnt, E, nbuckets);
    bucket_scan_kernel<<<1, 256, 0, stream>>>(bktcnt, bktbase, bcur, rowptr + N,
                                              nbuckets, E);
    bin_kernel<<<nbins, 256, 0, stream>>>(src, dst, bcur, pairs, E, nbuckets);
    bucket_build_kernel<<<nbuckets, 256, 0, stream>>>(bktbase, pairs, rowptr,
                                                      dinv, colsrc, N);

    // ---- layer 1 feature transform: Wt fragment-pack + MFMA gemm1 ----
    wt_kernel<<<64, 256, 0, stream>>>(W1, wtp);
    gemm1_mfma_kernel<<<(N + 63) / 64, 256, 0, stream>>>(x, wtp, dinv, h1b, N);

    // ---- layer-1 pull: 2 passes x 2 slices (pairs now dead -> agg) ----
    {
        int blocks = (N + 15) / 16;
        for (int p = 0; p < 2; p++) {
            const unsigned* ha = h1b + (size_t)(2 * p) * N * 16;
            const unsigned* hb = h1b + (size_t)(2 * p + 1) * N * 16;
            unsigned* aa = agg + (size_t)(2 * p) * N * 16;
            unsigned* ab = agg + (size_t)(2 * p + 1) * N * 16;
            l1_pass2_kernel<<<blocks, 256, 0, stream>>>(rowptr, colsrc, ha, hb, aa, ab, N);
        }
    }

    // ---- gemm2 (+bias/relu, pre-scale) ----
    gemm2_kernel<<<(N + 15) / 16, 256, 0, stream>>>(agg, dinv, b1, W2, h2s, N);

    // ---- fused pull-aggregation 2 + bias + log_softmax ----
    l2_kernel<<<(N + 3) / 4, 256, 0, stream>>>(rowptr, colsrc, dinv, h2s, b2, out, N);
}

// Round 13
// 205.345 us; speedup vs baseline: 1.3716x; 1.0503x over previous
//
#include <hip/hip_runtime.h>
#include <math.h>

// GCN, N=50000 nodes, E=800000 edges, F_IN=128, H=128, C=16. f32 in/out; edges int32.
//
// R2: CSR-by-dst pull aggregation (no float atomics), dinv pre-scaling.
// R3-R6: scan, bf16 h1 staging, counting-sort CSR, vectorized gathers.
// R7: L2-resident feature-slice passes for l1. R8: MFMA gemm1 (hi/lo split-A).
// R9: W1 pre-swizzled to MFMA fragment order. R10b: bf16 packed agg.
// R11: reverted coop CSR (grid.sync pinned occupancy). R12: 2 slices/pass (neutral).
// R13: gemm2 fused into the l1 passes. relu is elementwise, so
//      h2 = sum_p relu(dinv*agg_p + b1_p) @ W2_p distributes over slice passes:
//      each pass dots its relu'd 64-feat rows with a 64x16 W2 slice in LDS and
//      accumulates h2s (pass 0 stores, pass 1 atomicAdd). Deletes the 25.6 MB
//      agg round trip, the gemm2 kernel, and one bf16 rounding of agg.

#define NBUCKET_SHIFT 8                   // bucket = dst >> 8 (256 nodes/bucket)
#define BIN_CHUNK 4096                    // edges per binning block

typedef __bf16 bf16x8 __attribute__((ext_vector_type(8)));
typedef float  f32x4  __attribute__((ext_vector_type(4)));

__device__ __forceinline__ unsigned short pack_bf16(float f) {
    unsigned u = __float_as_uint(f);
    return (unsigned short)((u + 0x7fffu + ((u >> 16) & 1u)) >> 16);   // RNE
}

__device__ __forceinline__ unsigned pack_bf16x2(float a, float b) {
    return ((unsigned)pack_bf16(b) << 16) | pack_bf16(a);
}

__device__ __forceinline__ float2 unpack_bf16x2(unsigned u) {
    return make_float2(__uint_as_float(u << 16), __uint_as_float(u & 0xffff0000u));
}

__device__ __forceinline__ void acc_u4(float* a, uint4 v) {
    float2 t;
    t = unpack_bf16x2(v.x); a[0] += t.x; a[1] += t.y;
    t = unpack_bf16x2(v.y); a[2] += t.x; a[3] += t.y;
    t = unpack_bf16x2(v.z); a[4] += t.x; a[5] += t.y;
    t = unpack_bf16x2(v.w); a[6] += t.x; a[7] += t.y;
}

// ---------------- CSR build phase 1: per-bucket edge counts (LDS-staged) ------
__global__ __launch_bounds__(256)
void bucket_count_kernel(const int* __restrict__ dst, int* __restrict__ bktcnt,
                         int E, int nbuckets) {
    __shared__ int cnt[256];
    const int tid = threadIdx.x;
    cnt[tid] = 0;
    __syncthreads();
    const int e0 = blockIdx.x * BIN_CHUNK;
    const int n = min(BIN_CHUNK, E - e0);
    for (int i = tid; i < n; i += 256)
        atomicAdd(&cnt[dst[e0 + i] >> NBUCKET_SHIFT], 1);
    __syncthreads();
    if (tid < nbuckets && cnt[tid] > 0) atomicAdd(&bktcnt[tid], cnt[tid]);
}

// ---------------- phase 2: scan bucket counts -> bktbase, seed bin cursors ----
__global__ __launch_bounds__(256)
void bucket_scan_kernel(const int* __restrict__ bktcnt, int* __restrict__ bktbase,
                        int* __restrict__ bcur, int* __restrict__ rowptrN,
                        int nbuckets, int E) {
    __shared__ int sm[256];
    const int t = threadIdx.x;
    int v = (t < nbuckets) ? bktcnt[t] : 0;
    sm[t] = v;
    __syncthreads();
#pragma unroll
    for (int off = 1; off < 256; off <<= 1) {
        int u = (t >= off) ? sm[t - off] : 0;
        __syncthreads();
        sm[t] += u;
        __syncthreads();
    }
    int excl = sm[t] - v;
    if (t < nbuckets) { bktbase[t] = excl; bcur[t] = excl; }
    if (t == nbuckets - 1) bktbase[nbuckets] = excl + v;   // == E
    if (t == 0) *rowptrN = E;
}

// ---------------- phase 3: bin edges into bucket-major pair array -------------
__global__ __launch_bounds__(256)
void bin_kernel(const int* __restrict__ src, const int* __restrict__ dst,
                int* __restrict__ bcur, uint2* __restrict__ pairs, int E, int nbuckets) {
    __shared__ uint2 spair[BIN_CHUNK];   // 32 KB
    __shared__ int bcnt[256];
    __shared__ int bbase[256];
    const int tid = threadIdx.x;
    const int e0 = blockIdx.x * BIN_CHUNK;
    const int cnt = min(BIN_CHUNK, E - e0);

    if (tid < nbuckets) bcnt[tid] = 0;
    __syncthreads();

    for (int i = tid; i < cnt; i += 256) {
        int s = src[e0 + i], d = dst[e0 + i];
        spair[i] = make_uint2((unsigned)s, (unsigned)d);
        atomicAdd(&bcnt[d >> NBUCKET_SHIFT], 1);
    }
    __syncthreads();

    if (tid < nbuckets) {
        int c = bcnt[tid];
        bbase[tid] = (c > 0) ? atomicAdd(&bcur[tid], c) : 0;
        bcnt[tid] = 0;   // reuse as local cursor
    }
    __syncthreads();

    for (int i = tid; i < cnt; i += 256) {
        uint2 p = spair[i];
        int b = (int)(p.y >> NBUCKET_SHIFT);
        int off = atomicAdd(&bcnt[b], 1);
        pairs[bbase[b] + off] = p;
    }
}

// ---------------- phase 4: per-bucket rowptr + dinv + colsrc ------------------
__global__ __launch_bounds__(256)
void bucket_build_kernel(const int* __restrict__ bktbase, const uint2* __restrict__ pairs,
                         int* __restrict__ rowptr, float* __restrict__ dinv,
                         int* __restrict__ colsrc, int N) {
    __shared__ int cnt[256];
    __shared__ int sm[256];
    const int tid = threadIdx.x;
    const int nb0 = blockIdx.x << NBUCKET_SHIFT;
    const int lo = bktbase[blockIdx.x], hi = bktbase[blockIdx.x + 1];

    cnt[tid] = 0;
    __syncthreads();
    for (int i = lo + tid; i < hi; i += 256)
        atomicAdd(&cnt[(int)pairs[i].y - nb0], 1);
    __syncthreads();

    int v = cnt[tid];
    sm[tid] = v;
    __syncthreads();
#pragma unroll
    for (int off = 1; off < 256; off <<= 1) {
        int u = (tid >= off) ? sm[tid - off] : 0;
        __syncthreads();
        sm[tid] += u;
        __syncthreads();
    }
    int excl = sm[tid] - v;
    int node = nb0 + tid;
    if (node < N) {
        rowptr[node] = lo + excl;
        dinv[node] = rsqrtf((float)v + 1.0f);   // +1 self-loop
    }
    __syncthreads();
    cnt[tid] = lo + excl;   // reuse as scatter cursor
    __syncthreads();
    for (int i = lo + tid; i < hi; i += 256) {
        uint2 p = pairs[i];
        int pos = atomicAdd(&cnt[(int)p.y - nb0], 1);
        colsrc[pos] = (int)p.x;
    }
}

// ---------------- W1 -> MFMA-fragment-order bf16 pack (one-shot) --------------
__global__ __launch_bounds__(256)
void wt_kernel(const float* __restrict__ W, unsigned short* __restrict__ wtp) {
    int idx = blockIdx.x * 256 + threadIdx.x;    // 0..16383
    int j    = idx & 7;
    int lane = (idx >> 3) & 63;
    int ks   = (idx >> 9) & 3;
    int t    = idx >> 11;
    int n = t * 16 + (lane & 15);
    int k = ks * 32 + ((lane >> 4) << 3) + j;
    wtp[idx] = pack_bf16(W[k * 128 + n]);
}

// ---------------- gemm1: MFMA bf16, hi/lo split-A ----------------
__global__ __launch_bounds__(256)
void gemm1_mfma_kernel(const float* __restrict__ x, const unsigned short* __restrict__ wtp,
                       const float* __restrict__ dinv, unsigned* __restrict__ h1b, int N) {
    __shared__ float lds[4][16 * 132];   // 33792 B
    const int tid = threadIdx.x, wave = tid >> 6, lane = tid & 63;
    const int q = lane >> 4, m = lane & 15;
    const int row0 = blockIdx.x * 64 + wave * 16;
    const int row = row0 + m;
    const int rowc = (row < N) ? row : (N - 1);   // clamp (OOB rows masked at store)

    f32x4 acc[8];
#pragma unroll
    for (int t = 0; t < 8; t++) acc[t] = (f32x4)0.0f;

#pragma unroll
    for (int ks = 0; ks < 4; ks++) {
        const float4* xp = (const float4*)(x + (size_t)rowc * 128 + ks * 32 + q * 8);
        float4 f0 = xp[0], f1 = xp[1];
        float fv[8] = {f0.x, f0.y, f0.z, f0.w, f1.x, f1.y, f1.z, f1.w};
        bf16x8 ah, al;
#pragma unroll
        for (int j = 0; j < 8; j++) {
            __bf16 h = (__bf16)fv[j];
            ah[j] = h;
            al[j] = (__bf16)(fv[j] - (float)h);
        }
#pragma unroll
        for (int t = 0; t < 8; t++) {
            bf16x8 b = *(const bf16x8*)(wtp + (size_t)(t * 4 + ks) * 512 + lane * 8);
            acc[t] = __builtin_amdgcn_mfma_f32_16x16x32_bf16(ah, b, acc[t], 0, 0, 0);
            acc[t] = __builtin_amdgcn_mfma_f32_16x16x32_bf16(al, b, acc[t], 0, 0, 0);
        }
    }

#pragma unroll
    for (int t = 0; t < 8; t++)
#pragma unroll
        for (int r = 0; r < 4; r++)
            lds[wave][(q * 4 + r) * 132 + t * 16 + m] = acc[t][r];
    __syncthreads();

    const int r2 = lane >> 2, j = lane & 3;
    const int orow = row0 + r2;
    if (orow < N) {
        float dv = dinv[orow];
        const float* lrow = &lds[wave][r2 * 132];
#pragma unroll
        for (int s = 0; s < 4; s++) {
            float4 a = *(const float4*)(lrow + s * 32 + j * 8);
            float4 b = *(const float4*)(lrow + s * 32 + j * 8 + 4);
            uint4 p;
            p.x = pack_bf16x2(a.x * dv, a.y * dv);
            p.y = pack_bf16x2(a.z * dv, a.w * dv);
            p.z = pack_bf16x2(b.x * dv, b.y * dv);
            p.w = pack_bf16x2(b.z * dv, b.w * dv);
            ((uint4*)(h1b + (size_t)s * N * 16))[(size_t)orow * 4 + j] = p;
        }
    }
}

// ---------------- fused layer-1 pull + gemm2 partial, 2 slices per pass -------
// Wave = 4 nodes x 4 edge-groups x 4 uint4-chunks. After the xor-butterfly every
// lane holds its (node, chunk) full sums; g==0 lanes relu+write a 4x64 LDS tile;
// then 64 lanes = 4 nodes x 16 cols dot with the pass's 64x16 W2 slice and
// accumulate h2s (accumulate=0: plain store, 1: atomicAdd).
__global__ __launch_bounds__(256)
void l1_fused_kernel(const int* __restrict__ rowptr, const int* __restrict__ colsrc,
                     const float* __restrict__ dinv,
                     const unsigned* __restrict__ h1b_sa, const unsigned* __restrict__ h1b_sb,
                     const float* __restrict__ b1s, const float* __restrict__ W2s,
                     float* __restrict__ h2s, int N, int accumulate) {
    __shared__ float rows[4][4][64];   // [wave][node][feat], 4 KB
    __shared__ float w2s[64 * 16];     // [k][col], 4 KB
    const int tid = threadIdx.x;
    const int wave = tid >> 6, lane = tid & 63;
    const int n = lane >> 4;          // node 0..3 within wave
    const int g = (lane >> 2) & 3;    // edge group 0..3
    const int c = lane & 3;           // uint4 chunk 0..3
    const int d = blockIdx.x * 16 + wave * 4 + n;

    for (int i = tid; i < 256; i += 256)
        ((float4*)w2s)[i] = ((const float4*)W2s)[i];

    const uint4* hqa = (const uint4*)h1b_sa;   // node row = 4 uint4 per slice
    const uint4* hqb = (const uint4*)h1b_sb;

    if (d < N) {
        float a0[8], a1[8];
#pragma unroll
        for (int j = 0; j < 8; j++) { a0[j] = 0.0f; a1[j] = 0.0f; }

        if (g == 0) {                 // self-loop term, both slices
            acc_u4(a0, hqa[(size_t)d * 4 + c]);
            acc_u4(a1, hqb[(size_t)d * 4 + c]);
        }

        int i = rowptr[d], end = rowptr[d + 1];
        for (; i + 8 <= end; i += 8) {
            int sA = colsrc[i + g], sB = colsrc[i + 4 + g];
            uint4 vA0 = hqa[(size_t)sA * 4 + c];
            uint4 vA1 = hqb[(size_t)sA * 4 + c];
            uint4 vB0 = hqa[(size_t)sB * 4 + c];
            uint4 vB1 = hqb[(size_t)sB * 4 + c];
            acc_u4(a0, vA0); acc_u4(a1, vA1);
            acc_u4(a0, vB0); acc_u4(a1, vB1);
        }
        for (; i + 4 <= end; i += 4) {
            int sx = colsrc[i + g];
            uint4 v0 = hqa[(size_t)sx * 4 + c];
            uint4 v1 = hqb[(size_t)sx * 4 + c];
            acc_u4(a0, v0); acc_u4(a1, v1);
        }
        if (i < end && g < end - i) { // tail (<4 edges)
            int sx = colsrc[i + g];
            uint4 v0 = hqa[(size_t)sx * 4 + c];
            uint4 v1 = hqb[(size_t)sx * 4 + c];
            acc_u4(a0, v0); acc_u4(a1, v1);
        }

#pragma unroll
        for (int j = 0; j < 8; j++) { // combine 4 edge groups (16-lane butterfly)
            a0[j] += __shfl_xor(a0[j], 4, 64);
            a0[j] += __shfl_xor(a0[j], 8, 64);
            a1[j] += __shfl_xor(a1[j], 4, 64);
            a1[j] += __shfl_xor(a1[j], 8, 64);
        }
        if (g == 0) {                 // relu(dinv*agg + b1) -> LDS row tile
            float dv = dinv[d];
            const float4* b1q = (const float4*)b1s;
            float4 bA0 = b1q[2 * c],     bA1 = b1q[2 * c + 1];
            float4 bB0 = b1q[8 + 2 * c], bB1 = b1q[8 + 2 * c + 1];
            float bA[8] = {bA0.x, bA0.y, bA0.z, bA0.w, bA1.x, bA1.y, bA1.z, bA1.w};
            float bB[8] = {bB0.x, bB0.y, bB0.z, bB0.w, bB1.x, bB1.y, bB1.z, bB1.w};
#pragma unroll
            for (int j = 0; j < 8; j++) {
                rows[wave][n][c * 8 + j]      = fmaxf(a0[j] * dv + bA[j], 0.0f);
                rows[wave][n][32 + c * 8 + j] = fmaxf(a1[j] * dv + bB[j], 0.0f);
            }
        }
    }
    __syncthreads();

    // partial gemm2: lane = node n2 x col; h2s[d2][col] (+)= dinv*(row @ W2s)
    const int n2 = lane >> 4, col = lane & 15;
    const int d2 = blockIdx.x * 16 + wave * 4 + n2;
    if (d2 < N) {
        const float* r = &rows[wave][n2][0];
        float p = 0.0f;
#pragma unroll
        for (int k = 0; k < 64; k++)
            p = fmaf(r[k], w2s[k * 16 + col], p);
        p *= dinv[d2];
        if (accumulate) atomicAdd(&h2s[(size_t)d2 * 16 + col], p);
        else            h2s[(size_t)d2 * 16 + col] = p;
    }
}

// ---------------- fused layer-2 pull + log_softmax ----------------
__global__ __launch_bounds__(256)
void l2_kernel(const int* __restrict__ rowptr, const int* __restrict__ colsrc,
               const float* __restrict__ dinv, const float* __restrict__ h2s,
               const float* __restrict__ b2, float* __restrict__ out, int N) {
    const int tid = threadIdx.x;
    const int wave = tid >> 6, lane = tid & 63;
    const int g = lane >> 2;          // edge group 0..15
    const int c = lane & 3;           // float4 chunk (4 feats)
    const int d = blockIdx.x * 4 + wave;
    if (d >= N) return;
    const float4* h2q = (const float4*)h2s;  // row = 4 float4

    float4 acc = make_float4(0.f, 0.f, 0.f, 0.f);
    if (g == 0) acc = h2q[d * 4 + c];        // self-loop term
    int i = rowptr[d], end = rowptr[d + 1];
    for (; i + 16 <= end; i += 16) {
        int s = colsrc[i + g];
        float4 v = h2q[s * 4 + c];
        acc.x += v.x; acc.y += v.y; acc.z += v.z; acc.w += v.w;
    }
    if (i < end && g < end - i) {            // tail (<16 edges)
        int s = colsrc[i + g];
        float4 v = h2q[s * 4 + c];
        acc.x += v.x; acc.y += v.y; acc.z += v.z; acc.w += v.w;
    }
#pragma unroll
    for (int off = 4; off <= 32; off <<= 1) {
        acc.x += __shfl_xor(acc.x, off, 64);
        acc.y += __shfl_xor(acc.y, off, 64);
        acc.z += __shfl_xor(acc.z, off, 64);
        acc.w += __shfl_xor(acc.w, off, 64);
    }
    float dv = dinv[d];
    float4 b = ((const float4*)b2)[c];
    float4 val = make_float4(acc.x * dv + b.x, acc.y * dv + b.y,
                             acc.z * dv + b.z, acc.w * dv + b.w);
    float m = fmaxf(fmaxf(val.x, val.y), fmaxf(val.z, val.w));
    m = fmaxf(m, __shfl_xor(m, 1, 64));
    m = fmaxf(m, __shfl_xor(m, 2, 64));
    float e = expf(val.x - m) + expf(val.y - m) + expf(val.z - m) + expf(val.w - m);
    e += __shfl_xor(e, 1, 64);
    e += __shfl_xor(e, 2, 64);
    float lse = m + logf(e);
    if (g == 0)
        ((float4*)out)[d * 4 + c] =
            make_float4(val.x - lse, val.y - lse, val.z - lse, val.w - lse);
}

extern "C" void kernel_launch(void* const* d_in, const int* in_sizes, int n_in,
                              void* d_out, int out_size, void* d_ws, size_t ws_size,
                              hipStream_t stream) {
    const float* x  = (const float*)d_in[0];
    const int*  ei  = (const int*)d_in[1];
    const float* W1 = (const float*)d_in[2];
    const float* b1 = (const float*)d_in[3];
    const float* W2 = (const float*)d_in[4];
    const float* b2 = (const float*)d_in[5];
    float* out = (float*)d_out;

    const int N = in_sizes[0] / 128;   // 50000
    const int E = in_sizes[1] / 2;     // 800000
    const int* src = ei;
    const int* dst = ei + E;
    const int nbuckets = (N + 255) >> NBUCKET_SHIFT;   // 196 (< 256 required)
    const int nbins = (E + BIN_CHUNK - 1) / BIN_CHUNK; // 196

    // Workspace layout (4B units; prefix stays 16B-aligned):
    //   dinv    : N floats
    //   rowptr  : N+4 ints
    //   bktcnt  : 256 ints
    //   bktbase : 260 ints
    //   bcur    : 256 ints
    //   wtp     : 128*128 bf16 in MFMA fragment order (32 KB = 8192 int slots)
    //   colsrc  : E ints (3.2 MB)
    //   pairs   : E uint2 (6.4 MB)
    //   h1b     : N*64 uints (12.8 MB, slice-major 4 x N*16)
    //   h2s     : N*16 floats (3.2 MB)        total ~26 MB
    float*          wsf     = (float*)d_ws;
    float*          dinv    = wsf;
    int*            rowptr  = (int*)(wsf + N);
    int*            bktcnt  = rowptr + N + 4;
    int*            bktbase = bktcnt + 256;
    int*            bcur    = bktbase + 260;
    unsigned short* wtp     = (unsigned short*)(bcur + 256);
    int*            colsrc  = bcur + 256 + 8192;
    uint2*          pairs   = (uint2*)(colsrc + E);
    unsigned*       h1b     = (unsigned*)(pairs + E);
    float*          h2s     = (float*)(h1b + (size_t)N * 64);

    // ---- CSR build (4 kernels, full occupancy per phase) ----
    hipMemsetAsync(bktcnt, 0, 256 * sizeof(int), stream);
    bucket_count_kernel<<<nbins, 256, 0, stream>>>(dst, bktcnt, E, nbuckets);
    bucket_scan_kernel<<<1, 256, 0, stream>>>(bktcnt, bktbase, bcur, rowptr + N,
                                              nbuckets, E);
    bin_kernel<<<nbins, 256, 0, stream>>>(src, dst, bcur, pairs, E, nbuckets);
    bucket_build_kernel<<<nbuckets, 256, 0, stream>>>(bktbase, pairs, rowptr,
                                                      dinv, colsrc, N);

    // ---- layer 1 feature transform: Wt fragment-pack + MFMA gemm1 ----
    wt_kernel<<<64, 256, 0, stream>>>(W1, wtp);
    gemm1_mfma_kernel<<<(N + 63) / 64, 256, 0, stream>>>(x, wtp, dinv, h1b, N);

    // ---- fused layer-1 pull + gemm2 partials: 2 passes x 2 slices ----
    {
        int blocks = (N + 15) / 16;
        for (int p = 0; p < 2; p++) {
            const unsigned* ha = h1b + (size_t)(2 * p) * N * 16;
            const unsigned* hb = h1b + (size_t)(2 * p + 1) * N * 16;
            l1_fused_kernel<<<blocks, 256, 0, stream>>>(
                rowptr, colsrc, dinv, ha, hb,
                b1 + p * 64, W2 + (size_t)p * 64 * 16, h2s, N, p);
        }
    }

    // ---- fused pull-aggregation 2 + bias + log_softmax ----
    l2_kernel<<<(N + 3) / 4, 256, 0, stream>>>(rowptr, colsrc, dinv, h2s, b2, out, N);
}